// Round 5
// baseline (209.977 us; speedup 1.0000x reference)
//
#include <hip/hip_runtime.h>

#define N_TOK 2048
#define DD 512
#define FF 512
#define EE 64
#define TK 6
#define NG 66
#define RSLOT 12288   // N_TOK*TK
#define NSLOT 16384   // RSLOT + 2*N_TOK
#define BM 64
#define BN 64
#define NT1 (DD / 32)
#define NT2 (FF / 32)
#define MAXT 320      // max work items: sum ceil(cnt_g/BM) <= 255 + 64

typedef float f32x4 __attribute__((ext_vector_type(4)));
typedef __bf16 bf16x8 __attribute__((ext_vector_type(8)));
typedef short s16x8 __attribute__((ext_vector_type(8)));

__device__ __forceinline__ unsigned cvtpk(float lo, float hi) {
  unsigned r;
  asm("v_cvt_pk_bf16_f32 %0, %1, %2" : "=v"(r) : "v"(lo), "v"(hi));
  return r;
}

// ---------------- router: logits -> exp(l-max) -> top-6 + counts ----------------
__global__ void router_k(const float* __restrict__ x, const float* __restrict__ Wr,
                         int* __restrict__ top_i, float* __restrict__ top_w,
                         int* __restrict__ cnt) {
  int wave = threadIdx.x >> 6, lane = threadIdx.x & 63;
  int t0 = (blockIdx.x * 4 + wave) * 4;   // 4 tokens per wave
  const float* x0 = x + (size_t)t0 * DD;
  float a0 = 0.f, a1 = 0.f, a2 = 0.f, a3 = 0.f;
  for (int k = 0; k < DD; ++k) {
    float wv = Wr[k * EE + lane];
    a0 = fmaf(x0[k], wv, a0);
    a1 = fmaf(x0[DD + k], wv, a1);
    a2 = fmaf(x0[2 * DD + k], wv, a2);
    a3 = fmaf(x0[3 * DD + k], wv, a3);
  }
  float accs[4] = {a0, a1, a2, a3};
#pragma unroll
  for (int tt = 0; tt < 4; ++tt) {
    int t = t0 + tt;
    float acc = accs[tt];
    float m = acc;
#pragma unroll
    for (int s = 32; s; s >>= 1) m = fmaxf(m, __shfl_xor(m, s));
    float p = __expf(acc - m);   // unnormalized softmax; ratios identical
    int wi[TK]; float wv[TK];
#pragma unroll
    for (int it = 0; it < TK; ++it) {
      float v = p;
#pragma unroll
      for (int s = 32; s; s >>= 1) v = fmaxf(v, __shfl_xor(v, s));
      unsigned long long b = __ballot(p == v);
      int idx = __ffsll((unsigned long long)b) - 1;
      wi[it] = idx; wv[it] = v;
      if (lane == idx) p = -1.f;
    }
    float wsum = 0.f;
#pragma unroll
    for (int it = 0; it < TK; ++it) wsum += wv[it];
    if (lane < TK) {
      int si = 0; float sv = 0.f;
#pragma unroll
      for (int it = 0; it < TK; ++it) if (lane == it) { si = wi[it]; sv = wv[it]; }
      top_i[t * TK + lane] = si;
      top_w[t * TK + lane] = sv / wsum;
      atomicAdd(&cnt[si], 1);
    }
  }
}

// ---------------- offsets + dense work list ----------------
__global__ void offsets_k(const int* __restrict__ cnt, int* __restrict__ goff,
                          int* __restrict__ fill, int* __restrict__ wk_g,
                          int* __restrict__ wk_mt, int* __restrict__ nitems) {
  int i = threadIdx.x;
  if (i < EE) fill[i] = 0;
  if (i == 0) {
    int s = 0;
    for (int e = 0; e < EE; ++e) { goff[e] = s; s += cnt[e]; }
    goff[EE] = RSLOT;
    goff[EE + 1] = RSLOT + N_TOK;
    goff[EE + 2] = RSLOT + 2 * N_TOK;
    int m = 0;
    for (int g = 0; g < NG; ++g) {
      int c = goff[g + 1] - goff[g];
      int nt = (c + BM - 1) / BM;
      for (int t = 0; t < nt; ++t) { wk_g[m] = g; wk_mt[m] = t; ++m; }
    }
    nitems[0] = m;
  }
}

// ---------------- scatter: fill expert buckets (+ shared identity buckets) -----
__global__ void scatter_k(const int* __restrict__ top_i, const float* __restrict__ top_w,
                          const int* __restrict__ goff, int* __restrict__ fill,
                          int* __restrict__ btok, float* __restrict__ bw) {
  int idx = blockIdx.x * blockDim.x + threadIdx.x;
  if (idx < RSLOT) {
    int e = top_i[idx];
    int pos = goff[e] + atomicAdd(&fill[e], 1);
    btok[pos] = idx / TK;
    bw[pos] = top_w[idx];
  } else if (idx < NSLOT) {
    int j = idx - RSLOT;
    btok[idx] = j & (N_TOK - 1);
    bw[idx] = 1.0f;
  }
}

// ---------------- out = x (residual init) ----------------
__global__ void initout_k(const float* __restrict__ x, float* __restrict__ out, int n4) {
  int i = blockIdx.x * blockDim.x + threadIdx.x;
  if (i < n4) reinterpret_cast<f32x4*>(out)[i] = reinterpret_cast<const f32x4*>(x)[i];
}

// ---------------- GEMM1: H = silu(X*Wg) * (X*Wu), gathered rows -------------
// 64x64 block, 4 waves in 2x2, 2-deep register-prefetch pipeline, dense work list
__global__ __launch_bounds__(256) void gemm1_k(
    const float* __restrict__ x, const float* __restrict__ Wg, const float* __restrict__ Wu,
    const float* __restrict__ sWg, const float* __restrict__ sWu,
    const int* __restrict__ goff, const int* __restrict__ btok,
    const int* __restrict__ wk_g, const int* __restrict__ wk_mt,
    const int* __restrict__ nitems,
    short* __restrict__ H) {
  int item = blockIdx.y;
  if (item >= nitems[0]) return;
  int g = wk_g[item], mt = wk_mt[item];
  int s0g = goff[g], cnt = goff[g + 1] - s0g;
  int n0 = blockIdx.x * BN;
  const float* wgp = (g < EE) ? Wg + (size_t)g * DD * FF : sWg + (size_t)(g - EE) * DD * FF;
  const float* wup = (g < EE) ? Wu + (size_t)g * DD * FF : sWu + (size_t)(g - EE) * DD * FF;

  __shared__ short laA[2][4][BM][8];
  __shared__ short lbG[2][4][BN][8];
  __shared__ short lbU[2][4][BN][8];

  int tid = threadIdx.x;
  int lane = tid & 63;
  int w = tid >> 6;
  int wr = w >> 1, wc = w & 1;
  int lr = lane & 15, lgq = lane >> 4;

  int arow = tid >> 2, aseg = tid & 3;    // A staging: 4 threads/row, 8 k each
  int bcol = tid & 63, bkp = tid >> 6;    // B staging: col, kblk of 8

  int s0 = s0g + mt * BM;
  int aslot = (mt * BM + arow < cnt) ? s0 + arow : s0;
  const float* xrow = x + (size_t)btok[aslot] * DD + aseg * 8;
  const float* gb = wgp + n0 + bcol;
  const float* ub = wup + n0 + bcol;

  f32x4 accg[2][2], accu[2][2];
#pragma unroll
  for (int i = 0; i < 2; ++i)
#pragma unroll
    for (int j = 0; j < 2; ++j) {
      accg[i][j] = f32x4{0.f, 0.f, 0.f, 0.f};
      accu[i][j] = f32x4{0.f, 0.f, 0.f, 0.f};
    }

  // two register prefetch sets
  f32x4 a0_0, a0_1, a1_0, a1_1;
  float g0[8], u0[8], g1[8], u1[8];

#define LOAD1(S, kt) do { \
    const float* _p = xrow + (kt) * 32; \
    a##S##_0 = *reinterpret_cast<const f32x4*>(_p); \
    a##S##_1 = *reinterpret_cast<const f32x4*>(_p + 4); \
    int _kb = (kt) * 32 + bkp * 8; \
    _Pragma("unroll") \
    for (int _i = 0; _i < 8; ++_i) { \
      g##S[_i] = gb[(size_t)((_kb + _i) * FF)]; \
      u##S[_i] = ub[(size_t)((_kb + _i) * FF)]; \
    } \
  } while (0)

#define STORE1(S, b) do { \
    uint4 _va; \
    _va.x = cvtpk(a##S##_0[0], a##S##_0[1]); _va.y = cvtpk(a##S##_0[2], a##S##_0[3]); \
    _va.z = cvtpk(a##S##_1[0], a##S##_1[1]); _va.w = cvtpk(a##S##_1[2], a##S##_1[3]); \
    *reinterpret_cast<uint4*>(&laA[b][aseg][arow][0]) = _va; \
    uint4 _vg, _vu; \
    _vg.x = cvtpk(g##S[0], g##S[1]); _vg.y = cvtpk(g##S[2], g##S[3]); \
    _vg.z = cvtpk(g##S[4], g##S[5]); _vg.w = cvtpk(g##S[6], g##S[7]); \
    _vu.x = cvtpk(u##S[0], u##S[1]); _vu.y = cvtpk(u##S[2], u##S[3]); \
    _vu.z = cvtpk(u##S[4], u##S[5]); _vu.w = cvtpk(u##S[6], u##S[7]); \
    *reinterpret_cast<uint4*>(&lbG[b][bkp][bcol][0]) = _vg; \
    *reinterpret_cast<uint4*>(&lbU[b][bkp][bcol][0]) = _vu; \
  } while (0)

#define COMPUTE1(b) do { \
    bf16x8 _af[2], _bg[2], _bu[2]; \
    _Pragma("unroll") \
    for (int _i = 0; _i < 2; ++_i) \
      _af[_i] = *reinterpret_cast<const bf16x8*>(&laA[b][lgq][wr * 32 + _i * 16 + lr][0]); \
    _Pragma("unroll") \
    for (int _j = 0; _j < 2; ++_j) { \
      _bg[_j] = *reinterpret_cast<const bf16x8*>(&lbG[b][lgq][wc * 32 + _j * 16 + lr][0]); \
      _bu[_j] = *reinterpret_cast<const bf16x8*>(&lbU[b][lgq][wc * 32 + _j * 16 + lr][0]); \
    } \
    _Pragma("unroll") \
    for (int _i = 0; _i < 2; ++_i) \
      _Pragma("unroll") \
      for (int _j = 0; _j < 2; ++_j) { \
        accg[_i][_j] = __builtin_amdgcn_mfma_f32_16x16x32_bf16(_af[_i], _bg[_j], accg[_i][_j], 0, 0, 0); \
        accu[_i][_j] = __builtin_amdgcn_mfma_f32_16x16x32_bf16(_af[_i], _bu[_j], accu[_i][_j], 0, 0, 0); \
      } \
  } while (0)

  LOAD1(0, 0);
  LOAD1(1, 1);
  STORE1(0, 0);
  __syncthreads();
#pragma unroll 1
  for (int kt = 0; kt < NT1; kt += 2) {
    if (kt + 2 < NT1) LOAD1(0, kt + 2);
    COMPUTE1(0);
    STORE1(1, 1);
    __syncthreads();
    if (kt + 3 < NT1) LOAD1(1, kt + 3);
    COMPUTE1(1);
    if (kt + 2 < NT1) {
      STORE1(0, 0);
    }
    __syncthreads();
  }

  // epilogue: h = silu(g)*u -> bf16 H
#pragma unroll
  for (int i = 0; i < 2; ++i)
#pragma unroll
    for (int j = 0; j < 2; ++j)
#pragma unroll
      for (int r = 0; r < 4; ++r) {
        int mrow = wr * 32 + i * 16 + lgq * 4 + r;
        if (mt * BM + mrow < cnt) {
          float gg = accg[i][j][r];
          float uu = accu[i][j][r];
          float hv = (gg / (1.f + __expf(-gg))) * uu;
          int col = n0 + wc * 32 + j * 16 + lr;
          H[(size_t)(s0 + mrow) * FF + col] = (short)(cvtpk(hv, hv) & 0xffffu);
        }
      }
#undef LOAD1
#undef STORE1
#undef COMPUTE1
}

// ---------------- GEMM2: out[tok] += w * (H * Wd) ----------------
__global__ __launch_bounds__(256) void gemm2_k(
    const short* __restrict__ H, const float* __restrict__ Wd, const float* __restrict__ sWd,
    const int* __restrict__ goff, const int* __restrict__ btok, const float* __restrict__ bw,
    const int* __restrict__ wk_g, const int* __restrict__ wk_mt,
    const int* __restrict__ nitems,
    float* __restrict__ out) {
  int item = blockIdx.y;
  if (item >= nitems[0]) return;
  int g = wk_g[item], mt = wk_mt[item];
  int s0g = goff[g], cnt = goff[g + 1] - s0g;
  int n0 = blockIdx.x * BN;
  const float* wdp = (g < EE) ? Wd + (size_t)g * FF * DD : sWd + (size_t)(g - EE) * FF * DD;

  __shared__ short laA[2][4][BM][8];
  __shared__ short lbB[2][4][BN][8];

  int tid = threadIdx.x;
  int lane = tid & 63;
  int w = tid >> 6;
  int wr = w >> 1, wc = w & 1;
  int lr = lane & 15, lgq = lane >> 4;

  int arow = tid >> 2, aseg = tid & 3;
  int bcol = tid & 63, bkp = tid >> 6;

  int s0 = s0g + mt * BM;
  int aslot = (mt * BM + arow < cnt) ? s0 + arow : s0;
  const short* hrow = H + (size_t)aslot * FF + aseg * 8;
  const float* db = wdp + n0 + bcol;

  f32x4 acc[2][2];
#pragma unroll
  for (int i = 0; i < 2; ++i)
#pragma unroll
    for (int j = 0; j < 2; ++j) acc[i][j] = f32x4{0.f, 0.f, 0.f, 0.f};

  uint4 h0, h1;
  float d0[8], d1[8];

#define LOAD2(S, kt) do { \
    h##S = *reinterpret_cast<const uint4*>(hrow + (kt) * 32); \
    int _kb = (kt) * 32 + bkp * 8; \
    _Pragma("unroll") \
    for (int _i = 0; _i < 8; ++_i) d##S[_i] = db[(size_t)((_kb + _i) * DD)]; \
  } while (0)

#define STORE2(S, b) do { \
    *reinterpret_cast<uint4*>(&laA[b][aseg][arow][0]) = h##S; \
    uint4 _vd; \
    _vd.x = cvtpk(d##S[0], d##S[1]); _vd.y = cvtpk(d##S[2], d##S[3]); \
    _vd.z = cvtpk(d##S[4], d##S[5]); _vd.w = cvtpk(d##S[6], d##S[7]); \
    *reinterpret_cast<uint4*>(&lbB[b][bkp][bcol][0]) = _vd; \
  } while (0)

#define COMPUTE2(b) do { \
    bf16x8 _af[2], _bd[2]; \
    _Pragma("unroll") \
    for (int _i = 0; _i < 2; ++_i) \
      _af[_i] = *reinterpret_cast<const bf16x8*>(&laA[b][lgq][wr * 32 + _i * 16 + lr][0]); \
    _Pragma("unroll") \
    for (int _j = 0; _j < 2; ++_j) \
      _bd[_j] = *reinterpret_cast<const bf16x8*>(&lbB[b][lgq][wc * 32 + _j * 16 + lr][0]); \
    _Pragma("unroll") \
    for (int _i = 0; _i < 2; ++_i) \
      _Pragma("unroll") \
      for (int _j = 0; _j < 2; ++_j) \
        acc[_i][_j] = __builtin_amdgcn_mfma_f32_16x16x32_bf16(_af[_i], _bd[_j], acc[_i][_j], 0, 0, 0); \
  } while (0)

  LOAD2(0, 0);
  LOAD2(1, 1);
  STORE2(0, 0);
  __syncthreads();
#pragma unroll 1
  for (int kt = 0; kt < NT2; kt += 2) {
    if (kt + 2 < NT2) LOAD2(0, kt + 2);
    COMPUTE2(0);
    STORE2(1, 1);
    __syncthreads();
    if (kt + 3 < NT2) LOAD2(1, kt + 3);
    COMPUTE2(1);
    if (kt + 2 < NT2) {
      STORE2(0, 0);
    }
    __syncthreads();
  }

#pragma unroll
  for (int i = 0; i < 2; ++i)
#pragma unroll
    for (int r = 0; r < 4; ++r) {
      int mrow = wr * 32 + i * 16 + lgq * 4 + r;
      if (mt * BM + mrow < cnt) {
        int slot = s0 + mrow;
        int tok = btok[slot];
        float wv = bw[slot];
#pragma unroll
        for (int j = 0; j < 2; ++j) {
          int col = n0 + wc * 32 + j * 16 + lr;
          atomicAdd(&out[(size_t)tok * DD + col], acc[i][j][r] * wv);
        }
      }
    }
#undef LOAD2
#undef STORE2
#undef COMPUTE2
}

extern "C" void kernel_launch(void* const* d_in, const int* in_sizes, int n_in,
                              void* d_out, int out_size, void* d_ws, size_t ws_size,
                              hipStream_t stream) {
  const float* x   = (const float*)d_in[0];
  const float* Wr  = (const float*)d_in[1];
  const float* sWg = (const float*)d_in[2];
  const float* sWu = (const float*)d_in[3];
  const float* sWd = (const float*)d_in[4];
  const float* Wg  = (const float*)d_in[5];
  const float* Wu  = (const float*)d_in[6];
  const float* Wd  = (const float*)d_in[7];
  float* out = (float*)d_out;

  char* wsb = (char*)d_ws;
  size_t off = 0;
  short* H = (short*)(wsb + off);    off += (size_t)NSLOT * FF * 2;     // 16 MB
  int*   top_i = (int*)(wsb + off);  off += (size_t)RSLOT * 4;
  float* top_w = (float*)(wsb + off); off += (size_t)RSLOT * 4;
  int*   btok = (int*)(wsb + off);   off += (size_t)NSLOT * 4;
  float* bwt  = (float*)(wsb + off); off += (size_t)NSLOT * 4;
  int*   cnt  = (int*)(wsb + off);   off += 256;
  int*   fill = (int*)(wsb + off);   off += 256;
  int*   goff = (int*)(wsb + off);   off += 512;   // 67 ints used (EE+3) — was 256B: overflowed into wk_g
  int*   wk_g = (int*)(wsb + off);   off += MAXT * 4;
  int*   wk_mt = (int*)(wsb + off);  off += MAXT * 4;
  int*   nitems = (int*)(wsb + off); off += 256;

  hipMemsetAsync(cnt, 0, 256, stream);
  router_k<<<N_TOK / 16, 256, 0, stream>>>(x, Wr, top_i, top_w, cnt);
  offsets_k<<<1, 64, 0, stream>>>(cnt, goff, fill, wk_g, wk_mt, nitems);
  scatter_k<<<NSLOT / 256, 256, 0, stream>>>(top_i, top_w, goff, fill, btok, bwt);
  int n4 = out_size / 4;
  initout_k<<<(n4 + 255) / 256, 256, 0, stream>>>(x, out, n4);
  dim3 grid1(FF / BN, MAXT, 1);
  gemm1_k<<<grid1, 256, 0, stream>>>(x, Wg, Wu, sWg, sWu, goff, btok, wk_g, wk_mt, nitems, H);
  dim3 grid2(DD / BN, MAXT, 1);
  gemm2_k<<<grid2, 256, 0, stream>>>(H, Wd, sWd, goff, btok, bwt, wk_g, wk_mt, nitems, out);
}

// Round 6
// 196.906 us; speedup vs baseline: 1.0664x; 1.0664x over previous
//
#include <hip/hip_runtime.h>

#define N_TOK 2048
#define DD 512
#define FF 512
#define EE 64
#define TK 6
#define NG 66
#define RSLOT 12288   // N_TOK*TK
#define NSLOT 16384   // RSLOT + 2*N_TOK
#define BM 64
#define BN 64
#define NT 16         // 512/32 k-tiles
#define MAXT 320      // sum ceil(cnt_g/BM) <= 256 + 64

typedef float f32x4 __attribute__((ext_vector_type(4)));
typedef __bf16 bf16x8 __attribute__((ext_vector_type(8)));

__device__ __forceinline__ unsigned cvtpk(float lo, float hi) {
  unsigned r;
  asm("v_cvt_pk_bf16_f32 %0, %1, %2" : "=v"(r) : "v"(lo), "v"(hi));
  return r;
}

__device__ __forceinline__ bf16x8 pack8(f32x4 a, f32x4 b) {
  union { unsigned u[4]; bf16x8 v; } r;
  r.u[0] = cvtpk(a[0], a[1]); r.u[1] = cvtpk(a[2], a[3]);
  r.u[2] = cvtpk(b[0], b[1]); r.u[3] = cvtpk(b[2], b[3]);
  return r.v;
}

// async global->LDS DMA, 16B per lane; dest = wave-uniform base + lane*16
__device__ __forceinline__ void gll16(const void* g, void* l) {
  __builtin_amdgcn_global_load_lds(
      (const __attribute__((address_space(1))) unsigned int*)g,
      (__attribute__((address_space(3))) unsigned int*)l, 16, 0, 0);
}

// ---------------- router: 16 tokens/block, 4 waves k-split ----------------
__global__ __launch_bounds__(256) void router_k(
    const float* __restrict__ x, const float* __restrict__ Wr,
    int* __restrict__ top_i, float* __restrict__ top_w, int* __restrict__ cnt) {
  __shared__ float xs[16 * 512];          // 32 KB
  __shared__ float part[4][16][64];       // 16 KB
  int tid = threadIdx.x, lane = tid & 63, w = tid >> 6;
  int t0 = blockIdx.x * 16;

  const f32x4* xin = (const f32x4*)(x + (size_t)t0 * DD);
  f32x4* xs4 = (f32x4*)xs;
#pragma unroll
  for (int i = 0; i < 8; ++i) xs4[i * 256 + tid] = xin[i * 256 + tid];
  __syncthreads();

  float acc[16];
#pragma unroll
  for (int t = 0; t < 16; ++t) acc[t] = 0.f;
  for (int kk = 0; kk < 32; ++kk) {
    int k = w * 128 + kk * 4;
    float w0 = Wr[(size_t)(k + 0) * EE + lane];
    float w1 = Wr[(size_t)(k + 1) * EE + lane];
    float w2 = Wr[(size_t)(k + 2) * EE + lane];
    float w3 = Wr[(size_t)(k + 3) * EE + lane];
#pragma unroll
    for (int t = 0; t < 16; ++t) {
      f32x4 xv = *(const f32x4*)&xs[t * 512 + k];
      acc[t] = fmaf(xv[0], w0, acc[t]);
      acc[t] = fmaf(xv[1], w1, acc[t]);
      acc[t] = fmaf(xv[2], w2, acc[t]);
      acc[t] = fmaf(xv[3], w3, acc[t]);
    }
  }
#pragma unroll
  for (int t = 0; t < 16; ++t) part[w][t][lane] = acc[t];
  __syncthreads();

#pragma unroll
  for (int tt = 0; tt < 4; ++tt) {
    int t = w * 4 + tt;
    float l0 = part[0][t][lane] + part[1][t][lane] + part[2][t][lane] + part[3][t][lane];
    float m = l0;
#pragma unroll
    for (int s = 32; s; s >>= 1) m = fmaxf(m, __shfl_xor(m, s));
    float p = __expf(l0 - m);   // unnormalized; top-k ratios identical
    int wi[TK]; float wv[TK];
#pragma unroll
    for (int it = 0; it < TK; ++it) {
      float v = p;
#pragma unroll
      for (int s = 32; s; s >>= 1) v = fmaxf(v, __shfl_xor(v, s));
      unsigned long long b = __ballot(p == v);
      int idx = __ffsll((unsigned long long)b) - 1;
      wi[it] = idx; wv[it] = v;
      if (lane == idx) p = -1.f;
    }
    float wsum = 0.f;
#pragma unroll
    for (int it = 0; it < TK; ++it) wsum += wv[it];
    int tg = t0 + t;
    if (lane < TK) {
      int si = 0; float sv = 0.f;
#pragma unroll
      for (int it = 0; it < TK; ++it) if (lane == it) { si = wi[it]; sv = wv[it]; }
      top_i[tg * TK + lane] = si;
      top_w[tg * TK + lane] = sv / wsum;
      atomicAdd(&cnt[si], 1);
    }
  }
}

// ---------------- offsets + dense work list (1 wave, shfl prefix scans) -------
__global__ void offsets_k(const int* __restrict__ cnt, int* __restrict__ goff,
                          int* __restrict__ fill, int* __restrict__ wk_g,
                          int* __restrict__ wk_mt, int* __restrict__ nitems) {
  int i = threadIdx.x;  // 0..63
  fill[i] = 0;
  int c = cnt[i];
  int s = c;
#pragma unroll
  for (int d = 1; d < 64; d <<= 1) { int t = __shfl_up(s, d); if (i >= d) s += t; }
  goff[i] = s - c;
  if (i == 63) {
    goff[EE] = RSLOT;
    goff[EE + 1] = RSLOT + N_TOK;
    goff[EE + 2] = RSLOT + 2 * N_TOK;
  }
  int nt = (c + BM - 1) >> 6;
  int ts = nt;
#pragma unroll
  for (int d = 1; d < 64; d <<= 1) { int t = __shfl_up(ts, d); if (i >= d) ts += t; }
  int texcl = ts - nt;
  for (int t = 0; t < nt; ++t) { wk_g[texcl + t] = i; wk_mt[texcl + t] = t; }
  int tot = __shfl(ts, 63);
  wk_g[tot + i] = EE + (i >> 5);   // 64 shared-group tiles
  wk_mt[tot + i] = i & 31;
  if (i == 0) nitems[0] = tot + 64;
}

// ---------------- scatter ----------------
__global__ void scatter_k(const int* __restrict__ top_i, const float* __restrict__ top_w,
                          const int* __restrict__ goff, int* __restrict__ fill,
                          int* __restrict__ btok, float* __restrict__ bw) {
  int idx = blockIdx.x * blockDim.x + threadIdx.x;
  if (idx < RSLOT) {
    int e = top_i[idx];
    int pos = goff[e] + atomicAdd(&fill[e], 1);
    btok[pos] = idx / TK;
    bw[pos] = top_w[idx];
  } else if (idx < NSLOT) {
    int j = idx - RSLOT;
    btok[idx] = j & (N_TOK - 1);
    bw[idx] = 1.0f;
  }
}

// ---------------- out = x ----------------
__global__ void initout_k(const float* __restrict__ x, float* __restrict__ out, int n4) {
  int i = blockIdx.x * blockDim.x + threadIdx.x;
  if (i < n4) reinterpret_cast<f32x4*>(out)[i] = reinterpret_cast<const f32x4*>(x)[i];
}

// ---------------- GEMM1: H = silu(X*Wg) * (X*Wu) --------------------------
// 64x64, 4 waves 2x2, global_load_lds staging (f32 LDS, swizzled), 2-phase
__global__ __launch_bounds__(256) void gemm1_k(
    const float* __restrict__ x, const float* __restrict__ Wg, const float* __restrict__ Wu,
    const float* __restrict__ sWg, const float* __restrict__ sWu,
    const int* __restrict__ goff, const int* __restrict__ btok,
    const int* __restrict__ wk_g, const int* __restrict__ wk_mt,
    const int* __restrict__ nitems,
    short* __restrict__ H) {
  int item = blockIdx.y;
  if (item >= nitems[0]) return;
  int g = wk_g[item], mt = wk_mt[item];
  int s0g = goff[g], cnt = goff[g + 1] - s0g;
  int n0 = blockIdx.x * BN;
  const float* wgp = (g < EE) ? Wg + (size_t)g * DD * FF : sWg + (size_t)(g - EE) * DD * FF;
  const float* wup = (g < EE) ? Wu + (size_t)g * DD * FF : sWu + (size_t)(g - EE) * DD * FF;

  // per buffer: A [64][32] f32 (floats 0..2048), G [32][64] (2048..4096), U (4096..6144)
  __shared__ __align__(16) float lds[2][6144];   // 48 KB

  int tid = threadIdx.x;
  int lane = tid & 63;
  int w = tid >> 6;
  int wr = w >> 1, wc = w & 1;
  int lr = lane & 15, lgq = lane >> 4;
  int s0 = s0g + mt * BM;

  // staging: 24 chunks of 1KB; wave w handles chunks w*6..w*6+5
  const float* sp[6];
  int ldsoff[6], strf[6];
#pragma unroll
  for (int q = 0; q < 6; ++q) {
    int c = w * 6 + q;
    ldsoff[q] = c * 256;
    if (c < 8) {            // A: rows 8c..8c+8, 128B rows; swizzle (row&7)<<4 bytes
      int row = c * 8 + (lane >> 3);
      int tok = btok[s0 + row];
      sp[q] = x + (size_t)tok * DD + (((lane & 7) ^ (lane >> 3)) << 2);
      strf[q] = 32;
    } else if (c < 16) {    // G: k-rows 4cc..+4, 256B rows; swizzle ((k>>3)&3)<<5 bytes
      int cc = c - 8;
      int krow = cc * 4 + (lane >> 4);
      int colf = ((((lane & 15) << 4) ^ (((cc >> 1) & 3) << 5)) >> 2);
      sp[q] = wgp + (size_t)krow * FF + n0 + colf;
      strf[q] = 32 * FF;
    } else {                // U
      int cc = c - 16;
      int krow = cc * 4 + (lane >> 4);
      int colf = ((((lane & 15) << 4) ^ (((cc >> 1) & 3) << 5)) >> 2);
      sp[q] = wup + (size_t)krow * FF + n0 + colf;
      strf[q] = 32 * FF;
    }
  }

  f32x4 accg[2][2], accu[2][2];
#pragma unroll
  for (int i = 0; i < 2; ++i)
#pragma unroll
    for (int j = 0; j < 2; ++j) {
      accg[i][j] = f32x4{0.f, 0.f, 0.f, 0.f};
      accu[i][j] = f32x4{0.f, 0.f, 0.f, 0.f};
    }

  auto STAGE = [&](int b, int kt) {
#pragma unroll
    for (int q = 0; q < 6; ++q)
      gll16(sp[q] + (size_t)kt * strf[q], &lds[b][ldsoff[q]]);
  };
  auto COMPUTE = [&](int b) {
    const float* Am = &lds[b][0];
    const float* Gm = &lds[b][2048];
    const float* Um = &lds[b][4096];
    bf16x8 af[2], bg[2], bu[2];
#pragma unroll
    for (int i = 0; i < 2; ++i) {
      int row = wr * 32 + i * 16 + lr;
      int sw = (row & 7) << 2;
      f32x4 v0 = *(const f32x4*)&Am[row * 32 + ((lgq * 8) ^ sw)];
      f32x4 v1 = *(const f32x4*)&Am[row * 32 + ((lgq * 8 + 4) ^ sw)];
      af[i] = pack8(v0, v1);
    }
#pragma unroll
    for (int j = 0; j < 2; ++j) {
      int col = wc * 32 + j * 16 + lr;
      int cx = col ^ (lgq << 3);
      int kb = lgq * 8;
      f32x4 g0, g1, u0, u1;
#pragma unroll
      for (int i2 = 0; i2 < 4; ++i2) {
        g0[i2] = Gm[(kb + i2) * 64 + cx];
        g1[i2] = Gm[(kb + 4 + i2) * 64 + cx];
        u0[i2] = Um[(kb + i2) * 64 + cx];
        u1[i2] = Um[(kb + 4 + i2) * 64 + cx];
      }
      bg[j] = pack8(g0, g1);
      bu[j] = pack8(u0, u1);
    }
#pragma unroll
    for (int i = 0; i < 2; ++i)
#pragma unroll
      for (int j = 0; j < 2; ++j) {
        accg[i][j] = __builtin_amdgcn_mfma_f32_16x16x32_bf16(af[i], bg[j], accg[i][j], 0, 0, 0);
        accu[i][j] = __builtin_amdgcn_mfma_f32_16x16x32_bf16(af[i], bu[j], accu[i][j], 0, 0, 0);
      }
  };

  STAGE(0, 0);
  __syncthreads();
  int b = 0;
#pragma unroll 1
  for (int kt = 0; kt < NT; ++kt) {
    if (kt + 1 < NT) STAGE(b ^ 1, kt + 1);
    COMPUTE(b);
    __syncthreads();
    b ^= 1;
  }

  // epilogue: h = silu(g)*u -> bf16 H
#pragma unroll
  for (int i = 0; i < 2; ++i)
#pragma unroll
    for (int j = 0; j < 2; ++j)
#pragma unroll
      for (int r = 0; r < 4; ++r) {
        int mrow = wr * 32 + i * 16 + lgq * 4 + r;
        if (mt * BM + mrow < cnt) {
          float gg = accg[i][j][r];
          float uu = accu[i][j][r];
          float hv = (gg / (1.f + __expf(-gg))) * uu;
          int col = n0 + wc * 32 + j * 16 + lr;
          H[(size_t)(s0 + mrow) * FF + col] = (short)(cvtpk(hv, hv) & 0xffffu);
        }
      }
}

// ---------------- GEMM2: out[tok] += w * (H * Wd) ----------------
__global__ __launch_bounds__(256) void gemm2_k(
    const short* __restrict__ H, const float* __restrict__ Wd, const float* __restrict__ sWd,
    const int* __restrict__ goff, const int* __restrict__ btok, const float* __restrict__ bw,
    const int* __restrict__ wk_g, const int* __restrict__ wk_mt,
    const int* __restrict__ nitems,
    float* __restrict__ out) {
  int item = blockIdx.y;
  if (item >= nitems[0]) return;
  int g = wk_g[item], mt = wk_mt[item];
  int s0g = goff[g], cnt = goff[g + 1] - s0g;
  int n0 = blockIdx.x * BN;
  const float* wdp = (g < EE) ? Wd + (size_t)g * FF * DD : sWd + (size_t)(g - EE) * FF * DD;

  // per buffer: H [64][32] bf16 (shorts 0..2048), Wd [32][64] f32 (shorts 2048..6144)
  __shared__ __align__(16) short lds[2][6144];   // 24 KB

  int tid = threadIdx.x;
  int lane = tid & 63;
  int w = tid >> 6;
  int wr = w >> 1, wc = w & 1;
  int lr = lane & 15, lgq = lane >> 4;
  int s0 = s0g + mt * BM;

  // 12 chunks of 1KB; wave w handles chunks w*3..w*3+2
  const char* sp[3];
  int ldsbyte[3], strb[3];
#pragma unroll
  for (int q = 0; q < 3; ++q) {
    int c = w * 3 + q;
    ldsbyte[q] = c * 1024;
    if (c < 4) {            // H rows c*16..+16, 64B rows; swizzle (row&3)<<4 bytes
      int row = c * 16 + (lane >> 2);
      int slot = s0 + row;
      sp[q] = (const char*)(H + (size_t)slot * FF + (((lane & 3) ^ ((lane >> 2) & 3)) << 3));
      strb[q] = 64;
    } else {                // Wd k-rows, 256B rows; swizzle ((k>>3)&3)<<5 bytes
      int cc = c - 4;
      int krow = cc * 4 + (lane >> 4);
      int colf = ((((lane & 15) << 4) ^ (((cc >> 1) & 3) << 5)) >> 2);
      sp[q] = (const char*)(wdp + (size_t)krow * DD + n0 + colf);
      strb[q] = 32 * DD * 4;
    }
  }

  f32x4 acc[2][2];
#pragma unroll
  for (int i = 0; i < 2; ++i)
#pragma unroll
    for (int j = 0; j < 2; ++j) acc[i][j] = f32x4{0.f, 0.f, 0.f, 0.f};

  auto STAGE = [&](int b, int kt) {
#pragma unroll
    for (int q = 0; q < 3; ++q)
      gll16(sp[q] + (size_t)kt * strb[q], (char*)lds[b] + ldsbyte[q]);
  };
  auto COMPUTE = [&](int b) {
    const short* Hm = lds[b];
    const float* Bm = (const float*)(lds[b] + 2048);
    bf16x8 af[2], bd[2];
#pragma unroll
    for (int i = 0; i < 2; ++i) {
      int row = wr * 32 + i * 16 + lr;
      af[i] = *(const bf16x8*)&Hm[row * 32 + ((lgq * 8) ^ ((row & 3) << 3))];
    }
#pragma unroll
    for (int j = 0; j < 2; ++j) {
      int col = wc * 32 + j * 16 + lr;
      int cx = col ^ (lgq << 3);
      int kb = lgq * 8;
      f32x4 d0, d1;
#pragma unroll
      for (int i2 = 0; i2 < 4; ++i2) {
        d0[i2] = Bm[(kb + i2) * 64 + cx];
        d1[i2] = Bm[(kb + 4 + i2) * 64 + cx];
      }
      bd[j] = pack8(d0, d1);
    }
#pragma unroll
    for (int i = 0; i < 2; ++i)
#pragma unroll
      for (int j = 0; j < 2; ++j)
        acc[i][j] = __builtin_amdgcn_mfma_f32_16x16x32_bf16(af[i], bd[j], acc[i][j], 0, 0, 0);
  };

  STAGE(0, 0);
  __syncthreads();
  int b = 0;
#pragma unroll 1
  for (int kt = 0; kt < NT; ++kt) {
    if (kt + 1 < NT) STAGE(b ^ 1, kt + 1);
    COMPUTE(b);
    __syncthreads();
    b ^= 1;
  }

#pragma unroll
  for (int i = 0; i < 2; ++i)
#pragma unroll
    for (int r = 0; r < 4; ++r) {
      int mrow = wr * 32 + i * 16 + lgq * 4 + r;
      if (mt * BM + mrow < cnt) {
        int slot = s0 + mrow;
        int tok = btok[slot];
        float wv = bw[slot];
#pragma unroll
        for (int j = 0; j < 2; ++j) {
          int col = n0 + wc * 32 + j * 16 + lr;
          atomicAdd(&out[(size_t)tok * DD + col], acc[i][j][r] * wv);
        }
      }
    }
}

extern "C" void kernel_launch(void* const* d_in, const int* in_sizes, int n_in,
                              void* d_out, int out_size, void* d_ws, size_t ws_size,
                              hipStream_t stream) {
  const float* x   = (const float*)d_in[0];
  const float* Wr  = (const float*)d_in[1];
  const float* sWg = (const float*)d_in[2];
  const float* sWu = (const float*)d_in[3];
  const float* sWd = (const float*)d_in[4];
  const float* Wg  = (const float*)d_in[5];
  const float* Wu  = (const float*)d_in[6];
  const float* Wd  = (const float*)d_in[7];
  float* out = (float*)d_out;

  char* wsb = (char*)d_ws;
  size_t off = 0;
  short* H = (short*)(wsb + off);     off += (size_t)NSLOT * FF * 2;   // 16 MB
  int*   top_i = (int*)(wsb + off);   off += (size_t)RSLOT * 4;
  float* top_w = (float*)(wsb + off); off += (size_t)RSLOT * 4;
  int*   btok = (int*)(wsb + off);    off += (size_t)NSLOT * 4;
  float* bwt  = (float*)(wsb + off);  off += (size_t)NSLOT * 4;
  int*   cnt  = (int*)(wsb + off);    off += 256;
  int*   fill = (int*)(wsb + off);    off += 256;
  int*   goff = (int*)(wsb + off);    off += 512;   // 67 ints used
  int*   wk_g = (int*)(wsb + off);    off += MAXT * 4;
  int*   wk_mt = (int*)(wsb + off);   off += MAXT * 4;
  int*   nitems = (int*)(wsb + off);  off += 256;

  hipMemsetAsync(cnt, 0, 256, stream);
  router_k<<<N_TOK / 16, 256, 0, stream>>>(x, Wr, top_i, top_w, cnt);
  offsets_k<<<1, 64, 0, stream>>>(cnt, goff, fill, wk_g, wk_mt, nitems);
  scatter_k<<<NSLOT / 256, 256, 0, stream>>>(top_i, top_w, goff, fill, btok, bwt);
  int n4 = out_size / 4;
  initout_k<<<(n4 + 255) / 256, 256, 0, stream>>>(x, out, n4);
  dim3 grid1(FF / BN, MAXT, 1);
  gemm1_k<<<grid1, 256, 0, stream>>>(x, Wg, Wu, sWg, sWu, goff, btok, wk_g, wk_mt, nitems, H);
  dim3 grid2(DD / BN, MAXT, 1);
  gemm2_k<<<grid2, 256, 0, stream>>>(H, Wd, sWd, goff, btok, bwt, wk_g, wk_mt, nitems, out);
}